// Round 9
// baseline (350.713 us; speedup 1.0000x reference)
//
#include <hip/hip_runtime.h>
#include <hip/hip_cooperative_groups.h>

namespace cg = cooperative_groups;

#define N_EP     4096     // 2048 lines * 2 endpoints
#define NLINES   2048
#define KPTS     2048
#define CCH      256
#define HC_      128
#define WC_      128
#define MAXNBR   16
#define NPTS_ALL 6144     // N_EP + KPTS

// ---- output chunk offsets (floats) ----
#define O_PTS  0          // all_points (1,6144,2)       12288
#define O_SC   12288      // all_scores (1,6144)          6144
#define O_DESC 18432      // all_descs (1,256,6144)    1572864
#define O_NL   1591296    // new_lines (1,2048,2,2)       8192
#define O_LJI  1599488    // lines_junc_idx (1,2048,2)    4096
#define O_LS   1603584    // ls (1,2048)                  2048

// ---- ws offsets (4-byte words) ----
#define W_LS   0          // float[2048]
#define W_DEG  2048       // int[4096]
#define W_NBR  6144       // int[4096*16]
#define W_KEEP 71680      // int[2048]
#define W_JUNC 73728      // float[8192] (x,y interleaved)
#define W_V    81920      // float[256*4096] unnormalized junction descs

// ============================================================================
// Single cooperative kernel. 256 blocks x 1024 threads, 96 KB dynamic LDS
// (1 block/CU, grid == CU count). Phases:
//  A: per-block SoA endpoint stage; wave-per-point nbr lists (16 pts/blk),
//     wave-per-kp suppression (8 kp/blk), block 1 does ls.     [all blocks]
//  B: block 0 = single-block connected components + junction outputs (96 KB
//     LDS); blocks 1..255 concurrently stage their channel plane (64 KB) —
//     the 16 MB all_descriptors read hides under the serial cluster phase.
//  C: every block bilinear-samples its channel from LDS -> v_ws; masked
//     float4 kp-desc copy spread across all blocks.
//  D: blocks [0,64) = 256ch x 64junc tile norms + normalize epilogue.
// ============================================================================
__global__ __launch_bounds__(1024, 4) void k_fused(
    const float2* __restrict__ ep, const float2* __restrict__ kpts,
    const float* __restrict__ ksc, const float* __restrict__ lsc,
    const float* __restrict__ desc, const float* __restrict__ ad,
    int* __restrict__ deg, int* __restrict__ nbr, int* __restrict__ keep_ws,
    float* __restrict__ ws_ls, float* __restrict__ junc,
    float* __restrict__ v_ws, float* __restrict__ outp) {
    cg::grid_group gg = cg::this_grid();
    extern __shared__ int smem[];          // 24576 ints = 96 KB
    __shared__ int s_cnt[16];
    __shared__ float redf[16];
    __shared__ int wsum[16];
    __shared__ int changed;
    __shared__ float partial[16][64];
    __shared__ float inv64[64];

    const int b = blockIdx.x, t = threadIdx.x;
    const int lane = t & 63, wv = t >> 6;

    float* out_pts  = outp + O_PTS;
    float* out_sc   = outp + O_SC;
    float* out_desc = outp + O_DESC;
    float* out_nl   = outp + O_NL;
    float* out_lji  = outp + O_LJI;
    float* out_ls   = outp + O_LS;

    // ======================= Phase A =======================
    {
        float* s_x = (float*)smem;            // [4096]
        float* s_y = (float*)smem + N_EP;     // [4096]
        for (int i = t; i < N_EP; i += 1024) {
            float2 p = ep[i];
            s_x[i] = p.x; s_y[i] = p.y;
        }
        if (t < 16) s_cnt[t] = 0;
        __syncthreads();
        // neighbor lists: wave wv owns point i = b*16 + wv
        {
            int i = b * 16 + wv;
            float px = s_x[i], py = s_y[i];
            for (int k = 0; k < 64; ++k) {
                int j = lane + k * 64;
                float dx = px - s_x[j], dy = py - s_y[j];
                if (j != i && dx * dx + dy * dy <= 9.0f) {
                    int s = atomicAdd(&s_cnt[wv], 1);
                    if (s < MAXNBR) nbr[i * MAXNBR + s] = j;
                }
            }
        }
        // kp suppression: waves 0..7 own kp k = b*8 + wv
        if (wv < 8) {
            int k = b * 8 + wv;
            float2 p = kpts[k];
            int hit = 0;
            for (int q = 0; q < 64; ++q) {
                float dx = p.x - s_x[lane + q * 64];
                float dy = p.y - s_y[lane + q * 64];
                if (dx * dx + dy * dy < 16.0f) hit = 1;
            }
            int anyhit = __any(hit);
            if (lane == 0) {
                int keep = !anyhit;
                keep_ws[k] = keep;
                out_pts[2 * (N_EP + k)]     = keep ? p.x : 0.f;
                out_pts[2 * (N_EP + k) + 1] = keep ? p.y : 0.f;
                out_sc[N_EP + k] = keep ? ksc[k] : 0.f;
            }
        }
        __syncthreads();
        if (t < 16) deg[b * 16 + t] = min(s_cnt[t], MAXNBR);
        // ls normalize (block 1)
        if (b == 1) {
            float m = -1e30f;
            for (int i = t; i < NLINES; i += 1024) m = fmaxf(m, lsc[i]);
            for (int off = 32; off > 0; off >>= 1) m = fmaxf(m, __shfl_down(m, off));
            if (lane == 0) redf[wv] = m;
            __syncthreads();
            if (t == 0) {
                float mm = redf[0];
                for (int w = 1; w < 16; ++w) mm = fmaxf(mm, redf[w]);
                redf[0] = 1e-8f + mm;
            }
            __syncthreads();
            float denom = redf[0];
            for (int i = t; i < NLINES; i += 1024) {
                float v = lsc[i] / denom;
                ws_ls[i] = v;
                out_ls[i] = v;
            }
        }
    }
    __threadfence();
    gg.sync();

    // ======================= Phase B =======================
    if (b == 0) {
        int*   lab  = smem;                    // [4096]
        int*   rnk  = smem + N_EP;             // [4096] (deg_s during prop)
        float* fcnt = (float*)(smem + 2 * N_EP);
        float* fsx  = (float*)(smem + 3 * N_EP);
        float* fsy  = (float*)(smem + 4 * N_EP);
        float* fss  = (float*)(smem + 5 * N_EP);
        int*   deg_s = rnk;
        for (int i = t; i < N_EP; i += 1024) {
            lab[i] = i;
            deg_s[i] = deg[i];
            fcnt[i] = 0.f; fsx[i] = 0.f; fsy[i] = 0.f; fss[i] = 0.f;
        }
        for (int it = 0; it < 64; ++it) {
            __syncthreads();
            if (t == 0) changed = 0;
            __syncthreads();
            int f = 0;
            for (int i = t; i < N_EP; i += 1024) {
                int m = lab[i];
                int dg = deg_s[i];
                const int* nb = nbr + i * MAXNBR;
                for (int q = 0; q < dg; q++) m = min(m, lab[nb[q]]);
                m = min(m, lab[m]);     // pointer jump (lab[k] <= k invariant)
                if (m < lab[i]) { lab[i] = m; f = 1; }
            }
            if (f) atomicOr(&changed, 1);
            __syncthreads();
            if (changed == 0) break;
        }
        __syncthreads();
        // presence bitmap of roots -> dense rank (rnk reused; deg_s dead)
        for (int i = t; i < N_EP; i += 1024) rnk[i] = 0;
        __syncthreads();
        for (int i = t; i < N_EP; i += 1024) rnk[lab[i]] = 1;
        __syncthreads();
        {
            int b4 = t * 4;
            int a0 = rnk[b4], a1 = rnk[b4 + 1], a2 = rnk[b4 + 2], a3 = rnk[b4 + 3];
            int s = a0 + a1 + a2 + a3;
            int v = s;
            for (int off = 1; off < 64; off <<= 1) {
                int u = __shfl_up(v, off);
                if (lane >= off) v += u;
            }
            if (lane == 63) wsum[wv] = v;
            __syncthreads();
            if (wv == 0 && lane < 16) {
                int w = wsum[lane];
                for (int off = 1; off < 16; off <<= 1) {
                    int u = __shfl_up(w, off);
                    if (lane >= off) w += u;
                }
                wsum[lane] = w;
            }
            __syncthreads();
            int excl = ((wv == 0) ? 0 : wsum[wv - 1]) + v - s;
            rnk[b4] = excl;
            rnk[b4 + 1] = excl + a0;
            rnk[b4 + 2] = excl + a0 + a1;
            rnk[b4 + 3] = excl + a0 + a1 + a2;
        }
        __syncthreads();
        // relabel + LDS segment sums
        for (int i = t; i < N_EP; i += 1024) {
            int c = rnk[lab[i]];
            out_lji[i] = (float)c;
            float2 p = ep[i];
            atomicAdd(&fcnt[c], 1.f);
            atomicAdd(&fsx[c], p.x);
            atomicAdd(&fsy[c], p.y);
            atomicAdd(&fss[c], ws_ls[i >> 1]);
            lab[i] = c;                  // lab now holds cluster id
        }
        __syncthreads();
        // segment means -> junction outputs
        for (int j = t; j < N_EP; j += 1024) {
            float cm = fmaxf(fcnt[j], 1.f);
            float jx = fsx[j] / cm, jy = fsy[j] / cm;
            fsx[j] = jx; fsy[j] = jy;
            junc[2 * j] = jx; junc[2 * j + 1] = jy;
            out_pts[2 * j] = jx; out_pts[2 * j + 1] = jy;
            out_sc[j] = fss[j] / cm;
        }
        __syncthreads();
        // new_lines = junctions[clusters]
        for (int e = t; e < N_EP; e += 1024) {
            int c = lab[e];
            out_nl[2 * e] = fsx[c];
            out_nl[2 * e + 1] = fsy[c];
        }
        __syncthreads();
        // stage plane for channel 0 (cluster LDS dead now)
        float4* p4 = (float4*)smem;
        const float4* s4 = (const float4*)ad;
        for (int i = t; i < 4096; i += 1024) p4[i] = s4[i];
    } else {
        // stage plane for channel b (hides under block 0's cluster)
        float4* p4 = (float4*)smem;
        const float4* s4 = (const float4*)(ad + (size_t)b * (HC_ * WC_));
        for (int i = t; i < 4096; i += 1024) p4[i] = s4[i];
    }
    __threadfence();
    gg.sync();

    // ======================= Phase C =======================
    {
        const float* plane = (const float*)smem;
        const float2* j2 = (const float2*)junc;
        #pragma unroll
        for (int k = 0; k < 4; ++k) {
            int m = t + k * 1024;
            float2 pj = j2[m];
            float x = (pj.x - 3.5f) * (127.0f / 1019.5f);
            float y = (pj.y - 3.5f) * (127.0f / 1019.5f);
            float x0f = fminf(fmaxf(floorf(x), 0.f), WC_ - 1);
            float y0f = fminf(fmaxf(floorf(y), 0.f), HC_ - 1);
            float x1f = fminf(x0f + 1.f, WC_ - 1);
            float y1f = fminf(y0f + 1.f, HC_ - 1);
            float wx = x - x0f, wy = y - y0f;
            int x0 = (int)x0f, x1 = (int)x1f, y0 = (int)y0f, y1 = (int)y1f;
            float v = plane[y0 * WC_ + x0] * (1.f - wx) * (1.f - wy)
                    + plane[y0 * WC_ + x1] * wx * (1.f - wy)
                    + plane[y1 * WC_ + x0] * (1.f - wx) * wy
                    + plane[y1 * WC_ + x1] * wx * wy;
            v_ws[b * N_EP + m] = v;
        }
        // masked kp-desc copy: 131072 float4 groups over 256 blocks
        if (t < 512) {
            int gid = b * 512 + t;
            int c = gid >> 9, k4 = (gid & 511) * 4;
            float4 d = *(const float4*)(desc + c * KPTS + k4);
            float4 o;
            o.x = keep_ws[k4]     ? d.x : 0.f;
            o.y = keep_ws[k4 + 1] ? d.y : 0.f;
            o.z = keep_ws[k4 + 2] ? d.z : 0.f;
            o.w = keep_ws[k4 + 3] ? d.w : 0.f;
            *(float4*)(out_desc + c * NPTS_ALL + N_EP + k4) = o;
        }
    }
    __threadfence();
    gg.sync();

    // ======================= Phase D =======================
    if (b < 64) {
        float* tile = (float*)smem;      // [256][64]
        int m0 = b * 64;
        for (int cc = 0; cc < 16; ++cc) {
            int c = cc * 16 + wv;
            tile[c * 64 + lane] = v_ws[c * N_EP + m0 + lane];
        }
        __syncthreads();
        float s = 0.f;
        for (int k = 0; k < 16; ++k) {
            float v = tile[(wv * 16 + k) * 64 + lane];
            s += v * v;
        }
        partial[wv][lane] = s;
        __syncthreads();
        if (t < 64) {
            float tot = 0.f;
            for (int g = 0; g < 16; ++g) tot += partial[g][t];
            inv64[t] = 1.f / fmaxf(sqrtf(tot), 1e-12f);
        }
        __syncthreads();
        for (int cc = 0; cc < 16; ++cc) {
            int c = cc * 16 + wv;
            out_desc[c * NPTS_ALL + m0 + lane] = tile[c * 64 + lane] * inv64[lane];
        }
    }
}

extern "C" void kernel_launch(void* const* d_in, const int* in_sizes, int n_in,
                              void* d_out, int out_size, void* d_ws, size_t ws_size,
                              hipStream_t stream) {
    const float2* ep   = (const float2*)d_in[0];   // (1,2048,2,2) endpoints
    const float2* kpts = (const float2*)d_in[2];   // (1,2048,2)
    const float*  ksc  = (const float*)d_in[3];    // (1,2048)
    const float*  lsc  = (const float*)d_in[1];    // (1,2048)
    const float*  desc = (const float*)d_in[4];    // (1,256,2048)
    const float*  ad   = (const float*)d_in[5];    // (1,256,128,128)
    float* outp = (float*)d_out;

    float* wf    = (float*)d_ws;
    int*   wi    = (int*)d_ws;
    float* ws_ls = wf + W_LS;
    int*   deg   = wi + W_DEG;
    int*   nbr   = wi + W_NBR;
    int*   keep  = wi + W_KEEP;
    float* junc  = wf + W_JUNC;
    float* v_ws  = wf + W_V;

    void* args[] = {
        (void*)&ep, (void*)&kpts, (void*)&ksc, (void*)&lsc,
        (void*)&desc, (void*)&ad,
        (void*)&deg, (void*)&nbr, (void*)&keep, (void*)&ws_ls,
        (void*)&junc, (void*)&v_ws, (void*)&outp
    };
    hipLaunchCooperativeKernel((const void*)k_fused, dim3(256), dim3(1024),
                               args, 24576 * sizeof(int), stream);
}

// Round 10
// 60.505 us; speedup vs baseline: 5.7964x; 5.7964x over previous
//
#include <hip/hip_runtime.h>

#define N_EP     4096     // 2048 lines * 2 endpoints
#define NLINES   2048
#define KPTS     2048
#define CCH      256
#define HC_      128
#define WC_      128
#define MAXNBR   16
#define NPTS_ALL 6144     // N_EP + KPTS

// ---- output chunk offsets (floats) ----
#define O_PTS  0          // all_points (1,6144,2)       12288
#define O_SC   12288      // all_scores (1,6144)          6144
#define O_DESC 18432      // all_descs (1,256,6144)    1572864
#define O_NL   1591296    // new_lines (1,2048,2,2)       8192
#define O_LJI  1599488    // lines_junc_idx (1,2048,2)    4096
#define O_LS   1603584    // ls (1,2048)                  2048

// ---- ws offsets (4-byte words) ----
#define W_LS   0          // float[2048]
#define W_DEG  2048       // int[4096]
#define W_NBR  6144       // int[4096*16]
#define W_KEEP 71680      // int[2048]
#define W_JUNC 73728      // float[8192] (x,y interleaved)
#define W_V    81920      // float[256*4096] unnormalized junction descs

// ============================================================================
// K_FRONT (R6-proven): one block per point/keypoint, brute-force scans.
//   blocks [0,4096)    : neighbor lists of eps<=3 ball graph
//   blocks [4096,6144) : keypoint suppression
//   block  6144        : ls normalize
// ============================================================================
__global__ __launch_bounds__(256) void k_front(
    const float2* __restrict__ ep, const float2* __restrict__ kpts,
    const float* __restrict__ ksc, const float* __restrict__ lsc,
    int* __restrict__ deg, int* __restrict__ nbr, int* __restrict__ keep_ws,
    float* __restrict__ ws_ls,
    float* __restrict__ out_pts, float* __restrict__ out_sc,
    float* __restrict__ out_ls) {
    __shared__ float red[256];
    __shared__ int flag;
    int b = blockIdx.x, t = threadIdx.x;

    if (b < N_EP) {                       // ---- neighbor lists ----
        if (t == 0) flag = 0;
        __syncthreads();
        float2 p = ep[b];
        for (int j = t; j < N_EP; j += 256) {
            if (j == b) continue;
            float2 q = ep[j];
            float dx = p.x - q.x, dy = p.y - q.y;
            if (dx * dx + dy * dy <= 9.0f) {
                int s = atomicAdd(&flag, 1);
                if (s < MAXNBR) nbr[b * MAXNBR + s] = j;
            }
        }
        __syncthreads();
        if (t == 0) deg[b] = min(flag, MAXNBR);
    } else if (b < N_EP + KPTS) {         // ---- keypoint suppression ----
        int k = b - N_EP;
        if (t == 0) flag = 0;
        __syncthreads();
        float2 p = kpts[k];
        int hit = 0;
        for (int j = t; j < N_EP; j += 256) {
            float2 q = ep[j];
            float dx = p.x - q.x, dy = p.y - q.y;
            if (dx * dx + dy * dy < 16.0f) hit = 1;
        }
        if (__any(hit) && (t & 63) == 0) atomicOr(&flag, 1);
        __syncthreads();
        if (t == 0) {
            int keep = !flag;
            keep_ws[k] = keep;
            out_pts[2 * (N_EP + k)] = keep ? p.x : 0.f;
            out_pts[2 * (N_EP + k) + 1] = keep ? p.y : 0.f;
            out_sc[N_EP + k] = keep ? ksc[k] : 0.f;
        }
    } else {                              // ---- ls ----
        float m = -1e30f;
        for (int i = t; i < NLINES; i += 256) m = fmaxf(m, lsc[i]);
        red[t] = m; __syncthreads();
        for (int s = 128; s > 0; s >>= 1) {
            if (t < s) red[t] = fmaxf(red[t], red[t + s]);
            __syncthreads();
        }
        float denom = 1e-8f + red[0];
        for (int i = t; i < NLINES; i += 256) {
            float v = lsc[i] / denom;
            ws_ls[i] = v;
            out_ls[i] = v;
        }
    }
}

// ============================================================================
// K_CLUSTER: single-block connected components + dense relabel + junction
// outputs via LDS segment sums. NEW vs R6: propagation sweeps iterate only
// over the ACTIVE list (deg>0, ~10% of points; stored in rnk which is unused
// until after propagation). Isolated points keep lab[i]=i (their own root) —
// identical fixed point, ~10x less sweep work.
// Dynamic LDS (ints): lab[4096] rnk[4096] deg_s[4096] fcnt[4096] fsx[4096]
//                     fsy[4096] fss[4096]  = 112 KB
// ============================================================================
__global__ __launch_bounds__(1024) void k_cluster(
    const float2* __restrict__ ep, const int* __restrict__ deg,
    const int* __restrict__ nbr, const float* __restrict__ ws_ls,
    float* __restrict__ junc, float* __restrict__ out_pts,
    float* __restrict__ out_sc, float* __restrict__ out_nl,
    float* __restrict__ out_lji) {
    extern __shared__ int smem[];
    int*   lab   = smem;
    int*   rnk   = smem + N_EP;          // active list during propagation
    int*   deg_s = smem + 2 * N_EP;
    float* fcnt  = (float*)(smem + 3 * N_EP);
    float* fsx   = (float*)(smem + 4 * N_EP);
    float* fsy   = (float*)(smem + 5 * N_EP);
    float* fss   = (float*)(smem + 6 * N_EP);
    __shared__ int wsum[16];
    __shared__ int changed;
    __shared__ int nact;

    int t = threadIdx.x;
    int lane = t & 63, wv = t >> 6;
    if (t == 0) nact = 0;
    for (int i = t; i < N_EP; i += 1024) {
        lab[i] = i;
        deg_s[i] = deg[i];
        fcnt[i] = 0.f; fsx[i] = 0.f; fsy[i] = 0.f; fss[i] = 0.f;
    }
    __syncthreads();
    // build active list (points with neighbors) into rnk
    for (int i = t; i < N_EP; i += 1024) {
        if (deg_s[i] > 0) {
            int p = atomicAdd(&nact, 1);
            rnk[p] = i;
        }
    }
    __syncthreads();
    int na = nact;
    // min-label propagation with pointer jumping, active points only
    for (int it = 0; it < 64; ++it) {
        __syncthreads();
        if (t == 0) changed = 0;
        __syncthreads();
        int f = 0;
        for (int idx = t; idx < na; idx += 1024) {
            int i = rnk[idx];
            int m = lab[i];
            int dg = deg_s[i];
            const int* nb = nbr + i * MAXNBR;
            for (int q = 0; q < dg; q++) m = min(m, lab[nb[q]]);
            m = min(m, lab[m]);           // pointer jump (lab[k] <= k invariant)
            if (m < lab[i]) { lab[i] = m; f = 1; }
        }
        if (f) atomicOr(&changed, 1);
        __syncthreads();
        if (changed == 0) break;
    }
    __syncthreads();
    // presence bitmap of roots -> dense rank via exclusive scan (rnk reused)
    for (int i = t; i < N_EP; i += 1024) rnk[i] = 0;
    __syncthreads();
    for (int i = t; i < N_EP; i += 1024) rnk[lab[i]] = 1;
    __syncthreads();
    {
        int b4 = t * 4;
        int a0 = rnk[b4], a1 = rnk[b4 + 1], a2 = rnk[b4 + 2], a3 = rnk[b4 + 3];
        int s = a0 + a1 + a2 + a3;
        int v = s;
        for (int off = 1; off < 64; off <<= 1) {
            int u = __shfl_up(v, off);
            if (lane >= off) v += u;
        }
        if (lane == 63) wsum[wv] = v;
        __syncthreads();
        if (wv == 0 && lane < 16) {
            int w = wsum[lane];
            for (int off = 1; off < 16; off <<= 1) {
                int u = __shfl_up(w, off);
                if (lane >= off) w += u;
            }
            wsum[lane] = w;
        }
        __syncthreads();
        int excl = ((wv == 0) ? 0 : wsum[wv - 1]) + v - s;
        rnk[b4] = excl;
        rnk[b4 + 1] = excl + a0;
        rnk[b4 + 2] = excl + a0 + a1;
        rnk[b4 + 3] = excl + a0 + a1 + a2;
    }
    __syncthreads();
    // relabel + LDS segment sums
    for (int i = t; i < N_EP; i += 1024) {
        int c = rnk[lab[i]];
        out_lji[i] = (float)c;
        float2 p = ep[i];
        atomicAdd(&fcnt[c], 1.f);
        atomicAdd(&fsx[c], p.x);
        atomicAdd(&fsy[c], p.y);
        atomicAdd(&fss[c], ws_ls[i >> 1]);
        lab[i] = c;                       // lab now holds cluster id
    }
    __syncthreads();
    // segment means -> junction outputs
    for (int j = t; j < N_EP; j += 1024) {
        float cm = fmaxf(fcnt[j], 1.f);
        float jx = fsx[j] / cm, jy = fsy[j] / cm;
        fsx[j] = jx; fsy[j] = jy;
        junc[2 * j] = jx; junc[2 * j + 1] = jy;
        out_pts[2 * j] = jx; out_pts[2 * j + 1] = jy;
        out_sc[j] = fss[j] / cm;
    }
    __syncthreads();
    // new_lines = junctions[clusters]
    for (int e = t; e < N_EP; e += 1024) {
        int c = lab[e];
        out_nl[2 * e] = fsx[c];
        out_nl[2 * e + 1] = fsy[c];
    }
}

// ============================================================================
// K_SAMP: blocks [0,256): bilinear sample, 1 block/channel, plane in LDS
// (input read exactly once), no atomics. Blocks [256,384): float4 masked
// copy of keypoint descriptors.
// ============================================================================
__global__ __launch_bounds__(1024) void k_samp(const float* __restrict__ ad,
                                               const float* __restrict__ junc,
                                               const float* __restrict__ desc,
                                               const int* __restrict__ keep,
                                               float* __restrict__ v_ws,
                                               float* __restrict__ out_desc) {
    __shared__ float plane[HC_ * WC_];   // 64 KB
    int b = blockIdx.x, t = threadIdx.x;
    if (b < CCH) {
        int c = b;
        const float4* s4 = (const float4*)(ad + c * (HC_ * WC_));
        float4* p4 = (float4*)plane;
        #pragma unroll
        for (int i = 0; i < 4; ++i) p4[t + i * 1024] = s4[t + i * 1024];
        __syncthreads();
        const float2* j2 = (const float2*)junc;
        #pragma unroll
        for (int k = 0; k < 4; ++k) {
            int m = t + k * 1024;
            float2 pj = j2[m];
            float x = (pj.x - 3.5f) * (127.0f / 1019.5f);
            float y = (pj.y - 3.5f) * (127.0f / 1019.5f);
            float x0f = fminf(fmaxf(floorf(x), 0.f), WC_ - 1);
            float y0f = fminf(fmaxf(floorf(y), 0.f), HC_ - 1);
            float x1f = fminf(x0f + 1.f, WC_ - 1);
            float y1f = fminf(y0f + 1.f, HC_ - 1);
            float wx = x - x0f, wy = y - y0f;
            int x0 = (int)x0f, x1 = (int)x1f, y0 = (int)y0f, y1 = (int)y1f;
            float v = plane[y0 * WC_ + x0] * (1.f - wx) * (1.f - wy)
                    + plane[y0 * WC_ + x1] * wx * (1.f - wy)
                    + plane[y1 * WC_ + x0] * (1.f - wx) * wy
                    + plane[y1 * WC_ + x1] * wx * wy;
            v_ws[c * N_EP + m] = v;
        }
    } else {
        int gid = (b - CCH) * 1024 + t;      // 131072 float4 groups
        int c = gid >> 9;                    // 512 groups per channel
        int k4 = (gid & 511) * 4;
        float4 d = *(const float4*)(desc + c * KPTS + k4);
        float4 o;
        o.x = keep[k4]     ? d.x : 0.f;
        o.y = keep[k4 + 1] ? d.y : 0.f;
        o.z = keep[k4 + 2] ? d.z : 0.f;
        o.w = keep[k4 + 3] ? d.w : 0.f;
        *(float4*)(out_desc + c * NPTS_ALL + N_EP + k4) = o;
    }
}

// ============================================================================
// K_EPI: 64 blocks; 256ch x 64junc LDS tile — column norms + normalize,
// fully coalesced, no atomics.
// ============================================================================
__global__ __launch_bounds__(256) void k_epi(const float* __restrict__ v_ws,
                                             float* __restrict__ out_desc) {
    __shared__ float tile[CCH][64];
    __shared__ float partial[4][64];
    __shared__ float inv[64];
    int b = blockIdx.x, t = threadIdx.x;
    int m0 = b * 64;
    int q = t >> 6, ml = t & 63;
    for (int cc = 0; cc < 64; ++cc) {
        int c = cc * 4 + q;
        tile[c][ml] = v_ws[c * N_EP + m0 + ml];
    }
    __syncthreads();
    float s = 0.f;
    for (int c = q * 64; c < q * 64 + 64; ++c) {
        float v = tile[c][ml];
        s += v * v;
    }
    partial[q][ml] = s;
    __syncthreads();
    if (t < 64) {
        float tot = partial[0][t] + partial[1][t] + partial[2][t] + partial[3][t];
        inv[t] = 1.f / fmaxf(sqrtf(tot), 1e-12f);
    }
    __syncthreads();
    for (int cc = 0; cc < 64; ++cc) {
        int c = cc * 4 + q;
        out_desc[c * NPTS_ALL + m0 + ml] = tile[c][ml] * inv[ml];
    }
}

extern "C" void kernel_launch(void* const* d_in, const int* in_sizes, int n_in,
                              void* d_out, int out_size, void* d_ws, size_t ws_size,
                              hipStream_t stream) {
    const float* lines    = (const float*)d_in[0];   // (1,2048,2,2) == endpoints (4096,2)
    const float* lscores  = (const float*)d_in[1];   // (1,2048)
    const float* kpts     = (const float*)d_in[2];   // (1,2048,2)
    const float* kscores  = (const float*)d_in[3];   // (1,2048)
    const float* descs    = (const float*)d_in[4];   // (1,256,2048)
    const float* alldesc  = (const float*)d_in[5];   // (1,256,128,128)
    float* out = (float*)d_out;

    float* wf   = (float*)d_ws;
    int*   wi   = (int*)d_ws;
    float* ws_ls = wf + W_LS;
    int*   deg   = wi + W_DEG;
    int*   nbr   = wi + W_NBR;
    int*   keep  = wi + W_KEEP;
    float* junc  = wf + W_JUNC;
    float* v_ws  = wf + W_V;

    k_front<<<N_EP + KPTS + 1, 256, 0, stream>>>(
        (const float2*)lines, (const float2*)kpts, kscores, lscores,
        deg, nbr, keep, ws_ls, out + O_PTS, out + O_SC, out + O_LS);

    size_t lds_bytes = (size_t)(7 * N_EP) * sizeof(int);   // 112 KB
    k_cluster<<<1, 1024, lds_bytes, stream>>>(
        (const float2*)lines, deg, nbr, ws_ls, junc,
        out + O_PTS, out + O_SC, out + O_NL, out + O_LJI);

    k_samp<<<CCH + 128, 1024, 0, stream>>>(alldesc, junc, descs, keep, v_ws,
                                           out + O_DESC);

    k_epi<<<64, 256, 0, stream>>>(v_ws, out + O_DESC);
}

// Round 11
// 53.154 us; speedup vs baseline: 6.5980x; 1.1383x over previous
//
#include <hip/hip_runtime.h>

#define N_EP     4096     // 2048 lines * 2 endpoints
#define NLINES   2048
#define KPTS     2048
#define CCH      256
#define HC_      128
#define WC_      128
#define MAXNBR   16
#define NPTS_ALL 6144     // N_EP + KPTS
#define PPB      4        // points per k_front block (register-held)
#define NBR_BLKS (N_EP / PPB)    // 1024
#define KP_BLKS  (KPTS / PPB)    // 512

// ---- output chunk offsets (floats) ----
#define O_PTS  0          // all_points (1,6144,2)       12288
#define O_SC   12288      // all_scores (1,6144)          6144
#define O_DESC 18432      // all_descs (1,256,6144)    1572864
#define O_NL   1591296    // new_lines (1,2048,2,2)       8192
#define O_LJI  1599488    // lines_junc_idx (1,2048,2)    4096
#define O_LS   1603584    // ls (1,2048)                  2048

// ---- ws offsets (4-byte words) ----
#define W_LS   0          // float[2048]
#define W_DEG  2048       // int[4096]
#define W_NBR  6144       // int[4096*16]
#define W_KEEP 71680      // int[2048]
#define W_JUNC 73728      // float[8192] (x,y interleaved)
#define W_V    81920      // float[256*4096] unnormalized junction descs

// ============================================================================
// K_FRONT: 4 points per block held in REGISTERS (no LDS staging — R7/R8's
// occupancy trap avoided). Each thread scans its 16-candidate stride once,
// testing each ep[j] against all 4 points: L2 traffic /4 (200->50 MB), VALU
// work unchanged, occupancy unchanged.
//   blocks [0,1024)     : neighbor lists of eps<=3 ball graph
//   blocks [1024,1536)  : keypoint suppression (r<4)
//   block  1536         : ls normalize
// ============================================================================
__global__ __launch_bounds__(256) void k_front(
    const float2* __restrict__ ep, const float2* __restrict__ kpts,
    const float* __restrict__ ksc, const float* __restrict__ lsc,
    int* __restrict__ deg, int* __restrict__ nbr, int* __restrict__ keep_ws,
    float* __restrict__ ws_ls,
    float* __restrict__ out_pts, float* __restrict__ out_sc,
    float* __restrict__ out_ls) {
    __shared__ int s_cnt[PPB];
    __shared__ float red[256];
    int b = blockIdx.x, t = threadIdx.x;

    if (b < NBR_BLKS) {                   // ---- neighbor lists ----
        if (t < PPB) s_cnt[t] = 0;
        __syncthreads();
        int i0 = b * PPB;
        float2 p0 = ep[i0], p1 = ep[i0 + 1], p2 = ep[i0 + 2], p3 = ep[i0 + 3];
        for (int k = 0; k < N_EP / 256; ++k) {
            int j = t + k * 256;
            float2 q = ep[j];
            float d0x = p0.x - q.x, d0y = p0.y - q.y;
            float d1x = p1.x - q.x, d1y = p1.y - q.y;
            float d2x = p2.x - q.x, d2y = p2.y - q.y;
            float d3x = p3.x - q.x, d3y = p3.y - q.y;
            if (j != i0     && d0x * d0x + d0y * d0y <= 9.0f) {
                int s = atomicAdd(&s_cnt[0], 1);
                if (s < MAXNBR) nbr[i0 * MAXNBR + s] = j;
            }
            if (j != i0 + 1 && d1x * d1x + d1y * d1y <= 9.0f) {
                int s = atomicAdd(&s_cnt[1], 1);
                if (s < MAXNBR) nbr[(i0 + 1) * MAXNBR + s] = j;
            }
            if (j != i0 + 2 && d2x * d2x + d2y * d2y <= 9.0f) {
                int s = atomicAdd(&s_cnt[2], 1);
                if (s < MAXNBR) nbr[(i0 + 2) * MAXNBR + s] = j;
            }
            if (j != i0 + 3 && d3x * d3x + d3y * d3y <= 9.0f) {
                int s = atomicAdd(&s_cnt[3], 1);
                if (s < MAXNBR) nbr[(i0 + 3) * MAXNBR + s] = j;
            }
        }
        __syncthreads();
        if (t < PPB) deg[i0 + t] = min(s_cnt[t], MAXNBR);
    } else if (b < NBR_BLKS + KP_BLKS) {  // ---- keypoint suppression ----
        if (t < PPB) s_cnt[t] = 0;
        __syncthreads();
        int k0 = (b - NBR_BLKS) * PPB;
        float2 p0 = kpts[k0], p1 = kpts[k0 + 1], p2 = kpts[k0 + 2], p3 = kpts[k0 + 3];
        int h0 = 0, h1 = 0, h2 = 0, h3 = 0;
        for (int k = 0; k < N_EP / 256; ++k) {
            float2 q = ep[t + k * 256];
            float d0x = p0.x - q.x, d0y = p0.y - q.y;
            float d1x = p1.x - q.x, d1y = p1.y - q.y;
            float d2x = p2.x - q.x, d2y = p2.y - q.y;
            float d3x = p3.x - q.x, d3y = p3.y - q.y;
            if (d0x * d0x + d0y * d0y < 16.0f) h0 = 1;
            if (d1x * d1x + d1y * d1y < 16.0f) h1 = 1;
            if (d2x * d2x + d2y * d2y < 16.0f) h2 = 1;
            if (d3x * d3x + d3y * d3y < 16.0f) h3 = 1;
        }
        if (__any(h0) && (t & 63) == 0) atomicOr(&s_cnt[0], 1);
        if (__any(h1) && (t & 63) == 0) atomicOr(&s_cnt[1], 1);
        if (__any(h2) && (t & 63) == 0) atomicOr(&s_cnt[2], 1);
        if (__any(h3) && (t & 63) == 0) atomicOr(&s_cnt[3], 1);
        __syncthreads();
        if (t < PPB) {
            int kk = k0 + t;
            int keep = !s_cnt[t];
            float2 pk = kpts[kk];
            keep_ws[kk] = keep;
            out_pts[2 * (N_EP + kk)] = keep ? pk.x : 0.f;
            out_pts[2 * (N_EP + kk) + 1] = keep ? pk.y : 0.f;
            out_sc[N_EP + kk] = keep ? ksc[kk] : 0.f;
        }
    } else {                              // ---- ls normalize ----
        float m = -1e30f;
        for (int i = t; i < NLINES; i += 256) m = fmaxf(m, lsc[i]);
        red[t] = m; __syncthreads();
        for (int s = 128; s > 0; s >>= 1) {
            if (t < s) red[t] = fmaxf(red[t], red[t + s]);
            __syncthreads();
        }
        float denom = 1e-8f + red[0];
        for (int i = t; i < NLINES; i += 256) {
            float v = lsc[i] / denom;
            ws_ls[i] = v;
            out_ls[i] = v;
        }
    }
}

// ============================================================================
// K_CLUSTER: single-block connected components + dense relabel + junction
// outputs via LDS segment sums. Propagation sweeps iterate only over the
// ACTIVE list (deg>0, ~10% of points; stored in rnk which is unused until
// after propagation). Isolated points keep lab[i]=i — identical fixed point.
// Dynamic LDS (ints): lab[4096] rnk[4096] deg_s[4096] fcnt[4096] fsx[4096]
//                     fsy[4096] fss[4096]  = 112 KB
// ============================================================================
__global__ __launch_bounds__(1024) void k_cluster(
    const float2* __restrict__ ep, const int* __restrict__ deg,
    const int* __restrict__ nbr, const float* __restrict__ ws_ls,
    float* __restrict__ junc, float* __restrict__ out_pts,
    float* __restrict__ out_sc, float* __restrict__ out_nl,
    float* __restrict__ out_lji) {
    extern __shared__ int smem[];
    int*   lab   = smem;
    int*   rnk   = smem + N_EP;          // active list during propagation
    int*   deg_s = smem + 2 * N_EP;
    float* fcnt  = (float*)(smem + 3 * N_EP);
    float* fsx   = (float*)(smem + 4 * N_EP);
    float* fsy   = (float*)(smem + 5 * N_EP);
    float* fss   = (float*)(smem + 6 * N_EP);
    __shared__ int wsum[16];
    __shared__ int changed;
    __shared__ int nact;

    int t = threadIdx.x;
    int lane = t & 63, wv = t >> 6;
    if (t == 0) nact = 0;
    for (int i = t; i < N_EP; i += 1024) {
        lab[i] = i;
        deg_s[i] = deg[i];
        fcnt[i] = 0.f; fsx[i] = 0.f; fsy[i] = 0.f; fss[i] = 0.f;
    }
    __syncthreads();
    // build active list (points with neighbors) into rnk
    for (int i = t; i < N_EP; i += 1024) {
        if (deg_s[i] > 0) {
            int p = atomicAdd(&nact, 1);
            rnk[p] = i;
        }
    }
    __syncthreads();
    int na = nact;
    // min-label propagation with pointer jumping, active points only
    for (int it = 0; it < 64; ++it) {
        __syncthreads();
        if (t == 0) changed = 0;
        __syncthreads();
        int f = 0;
        for (int idx = t; idx < na; idx += 1024) {
            int i = rnk[idx];
            int m = lab[i];
            int dg = deg_s[i];
            const int* nb = nbr + i * MAXNBR;
            for (int q = 0; q < dg; q++) m = min(m, lab[nb[q]]);
            m = min(m, lab[m]);           // pointer jump (lab[k] <= k invariant)
            if (m < lab[i]) { lab[i] = m; f = 1; }
        }
        if (f) atomicOr(&changed, 1);
        __syncthreads();
        if (changed == 0) break;
    }
    __syncthreads();
    // presence bitmap of roots -> dense rank via exclusive scan (rnk reused)
    for (int i = t; i < N_EP; i += 1024) rnk[i] = 0;
    __syncthreads();
    for (int i = t; i < N_EP; i += 1024) rnk[lab[i]] = 1;
    __syncthreads();
    {
        int b4 = t * 4;
        int a0 = rnk[b4], a1 = rnk[b4 + 1], a2 = rnk[b4 + 2], a3 = rnk[b4 + 3];
        int s = a0 + a1 + a2 + a3;
        int v = s;
        for (int off = 1; off < 64; off <<= 1) {
            int u = __shfl_up(v, off);
            if (lane >= off) v += u;
        }
        if (lane == 63) wsum[wv] = v;
        __syncthreads();
        if (wv == 0 && lane < 16) {
            int w = wsum[lane];
            for (int off = 1; off < 16; off <<= 1) {
                int u = __shfl_up(w, off);
                if (lane >= off) w += u;
            }
            wsum[lane] = w;
        }
        __syncthreads();
        int excl = ((wv == 0) ? 0 : wsum[wv - 1]) + v - s;
        rnk[b4] = excl;
        rnk[b4 + 1] = excl + a0;
        rnk[b4 + 2] = excl + a0 + a1;
        rnk[b4 + 3] = excl + a0 + a1 + a2;
    }
    __syncthreads();
    // relabel + LDS segment sums
    for (int i = t; i < N_EP; i += 1024) {
        int c = rnk[lab[i]];
        out_lji[i] = (float)c;
        float2 p = ep[i];
        atomicAdd(&fcnt[c], 1.f);
        atomicAdd(&fsx[c], p.x);
        atomicAdd(&fsy[c], p.y);
        atomicAdd(&fss[c], ws_ls[i >> 1]);
        lab[i] = c;                       // lab now holds cluster id
    }
    __syncthreads();
    // segment means -> junction outputs
    for (int j = t; j < N_EP; j += 1024) {
        float cm = fmaxf(fcnt[j], 1.f);
        float jx = fsx[j] / cm, jy = fsy[j] / cm;
        fsx[j] = jx; fsy[j] = jy;
        junc[2 * j] = jx; junc[2 * j + 1] = jy;
        out_pts[2 * j] = jx; out_pts[2 * j + 1] = jy;
        out_sc[j] = fss[j] / cm;
    }
    __syncthreads();
    // new_lines = junctions[clusters]
    for (int e = t; e < N_EP; e += 1024) {
        int c = lab[e];
        out_nl[2 * e] = fsx[c];
        out_nl[2 * e + 1] = fsy[c];
    }
}

// ============================================================================
// K_SAMP: blocks [0,256): bilinear sample, 1 block/channel, plane in LDS
// (input read exactly once), no atomics. Blocks [256,384): float4 masked
// copy of keypoint descriptors.
// ============================================================================
__global__ __launch_bounds__(1024) void k_samp(const float* __restrict__ ad,
                                               const float* __restrict__ junc,
                                               const float* __restrict__ desc,
                                               const int* __restrict__ keep,
                                               float* __restrict__ v_ws,
                                               float* __restrict__ out_desc) {
    __shared__ float plane[HC_ * WC_];   // 64 KB
    int b = blockIdx.x, t = threadIdx.x;
    if (b < CCH) {
        int c = b;
        const float4* s4 = (const float4*)(ad + c * (HC_ * WC_));
        float4* p4 = (float4*)plane;
        #pragma unroll
        for (int i = 0; i < 4; ++i) p4[t + i * 1024] = s4[t + i * 1024];
        __syncthreads();
        const float2* j2 = (const float2*)junc;
        #pragma unroll
        for (int k = 0; k < 4; ++k) {
            int m = t + k * 1024;
            float2 pj = j2[m];
            float x = (pj.x - 3.5f) * (127.0f / 1019.5f);
            float y = (pj.y - 3.5f) * (127.0f / 1019.5f);
            float x0f = fminf(fmaxf(floorf(x), 0.f), WC_ - 1);
            float y0f = fminf(fmaxf(floorf(y), 0.f), HC_ - 1);
            float x1f = fminf(x0f + 1.f, WC_ - 1);
            float y1f = fminf(y0f + 1.f, HC_ - 1);
            float wx = x - x0f, wy = y - y0f;
            int x0 = (int)x0f, x1 = (int)x1f, y0 = (int)y0f, y1 = (int)y1f;
            float v = plane[y0 * WC_ + x0] * (1.f - wx) * (1.f - wy)
                    + plane[y0 * WC_ + x1] * wx * (1.f - wy)
                    + plane[y1 * WC_ + x0] * (1.f - wx) * wy
                    + plane[y1 * WC_ + x1] * wx * wy;
            v_ws[c * N_EP + m] = v;
        }
    } else {
        int gid = (b - CCH) * 1024 + t;      // 131072 float4 groups
        int c = gid >> 9;                    // 512 groups per channel
        int k4 = (gid & 511) * 4;
        float4 d = *(const float4*)(desc + c * KPTS + k4);
        float4 o;
        o.x = keep[k4]     ? d.x : 0.f;
        o.y = keep[k4 + 1] ? d.y : 0.f;
        o.z = keep[k4 + 2] ? d.z : 0.f;
        o.w = keep[k4 + 3] ? d.w : 0.f;
        *(float4*)(out_desc + c * NPTS_ALL + N_EP + k4) = o;
    }
}

// ============================================================================
// K_EPI: 64 blocks; 256ch x 64junc LDS tile — column norms + normalize,
// fully coalesced, no atomics.
// ============================================================================
__global__ __launch_bounds__(256) void k_epi(const float* __restrict__ v_ws,
                                             float* __restrict__ out_desc) {
    __shared__ float tile[CCH][64];
    __shared__ float partial[4][64];
    __shared__ float inv[64];
    int b = blockIdx.x, t = threadIdx.x;
    int m0 = b * 64;
    int q = t >> 6, ml = t & 63;
    for (int cc = 0; cc < 64; ++cc) {
        int c = cc * 4 + q;
        tile[c][ml] = v_ws[c * N_EP + m0 + ml];
    }
    __syncthreads();
    float s = 0.f;
    for (int c = q * 64; c < q * 64 + 64; ++c) {
        float v = tile[c][ml];
        s += v * v;
    }
    partial[q][ml] = s;
    __syncthreads();
    if (t < 64) {
        float tot = partial[0][t] + partial[1][t] + partial[2][t] + partial[3][t];
        inv[t] = 1.f / fmaxf(sqrtf(tot), 1e-12f);
    }
    __syncthreads();
    for (int cc = 0; cc < 64; ++cc) {
        int c = cc * 4 + q;
        out_desc[c * NPTS_ALL + m0 + ml] = tile[c][ml] * inv[ml];
    }
}

extern "C" void kernel_launch(void* const* d_in, const int* in_sizes, int n_in,
                              void* d_out, int out_size, void* d_ws, size_t ws_size,
                              hipStream_t stream) {
    const float* lines    = (const float*)d_in[0];   // (1,2048,2,2) == endpoints (4096,2)
    const float* lscores  = (const float*)d_in[1];   // (1,2048)
    const float* kpts     = (const float*)d_in[2];   // (1,2048,2)
    const float* kscores  = (const float*)d_in[3];   // (1,2048)
    const float* descs    = (const float*)d_in[4];   // (1,256,2048)
    const float* alldesc  = (const float*)d_in[5];   // (1,256,128,128)
    float* out = (float*)d_out;

    float* wf   = (float*)d_ws;
    int*   wi   = (int*)d_ws;
    float* ws_ls = wf + W_LS;
    int*   deg   = wi + W_DEG;
    int*   nbr   = wi + W_NBR;
    int*   keep  = wi + W_KEEP;
    float* junc  = wf + W_JUNC;
    float* v_ws  = wf + W_V;

    k_front<<<NBR_BLKS + KP_BLKS + 1, 256, 0, stream>>>(
        (const float2*)lines, (const float2*)kpts, kscores, lscores,
        deg, nbr, keep, ws_ls, out + O_PTS, out + O_SC, out + O_LS);

    size_t lds_bytes = (size_t)(7 * N_EP) * sizeof(int);   // 112 KB
    k_cluster<<<1, 1024, lds_bytes, stream>>>(
        (const float2*)lines, deg, nbr, ws_ls, junc,
        out + O_PTS, out + O_SC, out + O_NL, out + O_LJI);

    k_samp<<<CCH + 128, 1024, 0, stream>>>(alldesc, junc, descs, keep, v_ws,
                                           out + O_DESC);

    k_epi<<<64, 256, 0, stream>>>(v_ws, out + O_DESC);
}